// Round 1
// baseline (293.832 us; speedup 1.0000x reference)
//
#include <hip/hip_runtime.h>
#include <hip/hip_bf16.h>

// FeatureSimilarity l2: out[i][j] = -sqrt(max(sq[i] + sq[j] - 2*<f_i, f_j>, 0))
// N=8192, D=128, fp32 in/out. Write-bound (268 MB out, ~42 us floor at 6.3 TB/s).
// Strategy: bf16 MFMA for the F*F^T dot products (fp32 VALU can't reach the
// memory roofline: 17.2 GFLOP / 157 TF = 110 us). F is 2 MB in bf16 -> fully
// L2-resident, so MFMA fragments are loaded directly from global (no LDS).

typedef __attribute__((ext_vector_type(8))) short short8;    // 8 bf16 = 4 VGPRs
typedef __attribute__((ext_vector_type(4))) float float4v;   // MFMA acc

#define FS_N 8192
#define FS_D 128

// RNE fp32 -> bf16 (matches MFMA input rounding; self-contained bit twiddle)
static __device__ __forceinline__ unsigned short f32_to_bf16_rne(float x) {
    unsigned u = __float_as_uint(x);
    u += 0x7FFFu + ((u >> 16) & 1u);
    return (unsigned short)(u >> 16);
}
static __device__ __forceinline__ float bf16_to_f32(unsigned short b) {
    return __uint_as_float(((unsigned)b) << 16);
}

// Kernel 1: convert F (fp32) -> bf16 in ws, and sq[i] = sum(bf16(f_i)^2) in fp32.
// One wave per row: 64 lanes x float2 = 512 B coalesced load, 256 B coalesced store.
__global__ __launch_bounds__(256) void fs_convert_kernel(
        const float* __restrict__ in, unsigned short* __restrict__ fb,
        float* __restrict__ sq) {
    const int row  = (blockIdx.x << 2) | (threadIdx.x >> 6);  // 4 waves/block
    const int lane = threadIdx.x & 63;
    const float2 v = ((const float2*)(in + row * FS_D))[lane];
    const unsigned short b0 = f32_to_bf16_rne(v.x);
    const unsigned short b1 = f32_to_bf16_rne(v.y);
    ((ushort2*)(fb + row * FS_D))[lane] = make_ushort2(b0, b1);
    const float f0 = bf16_to_f32(b0), f1 = bf16_to_f32(b1);
    float s = f0 * f0 + f1 * f1;
    #pragma unroll
    for (int off = 32; off > 0; off >>= 1) s += __shfl_down(s, off);
    if (lane == 0) sq[row] = s;
}

// Kernel 2: per block, one 128x128 output tile. 4 waves in 2x2, each 64x64
// (4x4 tiles of 16x16x32 bf16 MFMA, K=128 = 4 ksteps). Fragments gathered
// straight from the L2-resident bf16 matrix.
__global__ __launch_bounds__(256) void fs_gemm_kernel(
        const unsigned short* __restrict__ fb, const float* __restrict__ sq,
        float* __restrict__ out) {
    const int ti   = blockIdx.x;          // row-tile
    const int tj   = blockIdx.y;          // col-tile
    const int wid  = threadIdx.x >> 6;
    const int lane = threadIdx.x & 63;
    const int wm   = wid >> 1, wn = wid & 1;
    const int l15  = lane & 15;
    const int quad = lane >> 4;

    const int arow = ti * 128 + wm * 64;  // A rows this wave covers (+0..63)
    const int brow = tj * 128 + wn * 64;  // B rows (= output cols)

    float4v acc[4][4];
    #pragma unroll
    for (int m = 0; m < 4; ++m)
        #pragma unroll
        for (int n = 0; n < 4; ++n)
            acc[m][n] = (float4v){0.f, 0.f, 0.f, 0.f};

    #pragma unroll
    for (int ks = 0; ks < 4; ++ks) {
        const int kofs = ks * 32 + quad * 8;   // each lane: 8 contiguous bf16
        short8 a[4], b[4];
        #pragma unroll
        for (int m = 0; m < 4; ++m)
            a[m] = *(const short8*)(fb + (arow + m * 16 + l15) * FS_D + kofs);
        #pragma unroll
        for (int n = 0; n < 4; ++n)
            b[n] = *(const short8*)(fb + (brow + n * 16 + l15) * FS_D + kofs);
        #pragma unroll
        for (int m = 0; m < 4; ++m)
            #pragma unroll
            for (int n = 0; n < 4; ++n)
                acc[m][n] = __builtin_amdgcn_mfma_f32_16x16x32_bf16(
                    a[m], b[n], acc[m][n], 0, 0, 0);
    }

    // Epilogue. C/D layout (16x16): col = lane&15, row = quad*4 + reg.
    // sq rows for a given (m): quad*4 + r, r=0..3 -> one aligned float4 load.
    #pragma unroll
    for (int m = 0; m < 4; ++m) {
        const float4v sqr = *(const float4v*)(sq + arow + m * 16 + quad * 4);
        #pragma unroll
        for (int n = 0; n < 4; ++n) {
            const int   col = brow + n * 16 + l15;
            const float sqc = sq[col];
            #pragma unroll
            for (int r = 0; r < 4; ++r) {
                const int row = arow + m * 16 + quad * 4 + r;
                float d2 = sqr[r] + sqc - 2.0f * acc[m][n][r];
                d2 = fmaxf(d2, 0.0f);
                out[row * FS_N + col] = -__builtin_sqrtf(d2);
            }
        }
    }
}

extern "C" void kernel_launch(void* const* d_in, const int* in_sizes, int n_in,
                              void* d_out, int out_size, void* d_ws, size_t ws_size,
                              hipStream_t stream) {
    const float* features = (const float*)d_in[0];
    float*       out      = (float*)d_out;

    // ws layout: [0, 2MB) bf16 features; [2MB, 2MB+32KB) fp32 row sum-of-squares
    unsigned short* fb = (unsigned short*)d_ws;
    float*          sq = (float*)((char*)d_ws + (size_t)FS_N * FS_D * sizeof(unsigned short));

    fs_convert_kernel<<<FS_N / 4, 256, 0, stream>>>(features, fb, sq);

    dim3 grid(FS_N / 128, FS_N / 128);
    fs_gemm_kernel<<<grid, 256, 0, stream>>>(fb, sq, out);
}

// Round 2
// 279.072 us; speedup vs baseline: 1.0529x; 1.0529x over previous
//
#include <hip/hip_runtime.h>
#include <hip/hip_bf16.h>

// FeatureSimilarity l2: out[i][j] = -sqrt(max(sq[i] + sq[j] - 2*<f_i, f_j>, 0))
// N=8192, D=128, fp32 in/out. Write-bound (268 MB out, ~42 us floor).
//
// R1 changes vs R0 (293 us):
//  1. F is pre-swizzled into MFMA fragment order fbT[rt][ks][lane][8] so every
//     fragment load is a coalesced 1 KB global_load_dwordx4 (R0 gathered 16 B
//     from 64 distinct cache lines per load -> ~8x L2 line amplification).
//  2. Epilogue writes the transposed element out[col][row] (bitwise-exact by
//     symmetry: MFMA dot(i,j)==dot(j,i)), making per-lane stores contiguous
//     float4 -> global_store_dwordx4, 4x fewer store instructions.

typedef __attribute__((ext_vector_type(8))) short short8;    // 8 bf16 = 4 VGPRs
typedef __attribute__((ext_vector_type(4))) float float4v;   // MFMA acc

#define FS_N 8192
#define FS_D 128

// RNE fp32 -> bf16 (matches MFMA input rounding)
static __device__ __forceinline__ unsigned short f32_to_bf16_rne(float x) {
    unsigned u = __float_as_uint(x);
    u += 0x7FFFu + ((u >> 16) & 1u);
    return (unsigned short)(u >> 16);
}
static __device__ __forceinline__ float bf16_to_f32(unsigned short b) {
    return __uint_as_float(((unsigned)b) << 16);
}

// Kernel 1: fp32 F -> bf16 in MFMA-fragment-swizzled layout
//   fbT[((rt*4 + ks)*64 + quad*16 + l15)*8 + e]  holds  F_bf16[rt*16+l15][ks*32+quad*8+e]
// and sq[row] = sum(bf16(f_row)^2) in fp32.
// One block = one 16-row tile (rt). thread t: row_local = t>>4, k-group g = t&15.
__global__ __launch_bounds__(256) void fs_convert_kernel(
        const float* __restrict__ in, unsigned short* __restrict__ fbT,
        float* __restrict__ sq) {
    const int rt = blockIdx.x;           // 0..511
    const int t  = threadIdx.x;
    const int rl = t >> 4;               // row within tile, 0..15
    const int g  = t & 15;               // 8-element k-group, 0..15
    const int row = rt * 16 + rl;

    const float4* src = (const float4*)(in + row * FS_D + g * 8);
    const float4 v0 = src[0];
    const float4 v1 = src[1];

    short8 packed;
    float s = 0.0f;
    {
        const float vv[8] = {v0.x, v0.y, v0.z, v0.w, v1.x, v1.y, v1.z, v1.w};
        #pragma unroll
        for (int e = 0; e < 8; ++e) {
            const unsigned short b = f32_to_bf16_rne(vv[e]);
            packed[e] = (short)b;
            const float f = bf16_to_f32(b);
            s += f * f;
        }
    }

    // swizzled store: ks = g>>2, quad = g&3, lane_in_frag = quad*16 + rl
    const int ks   = g >> 2;
    const int quad = g & 3;
    short8* dst = (short8*)(fbT + (((size_t)(rt * 4 + ks) * 64) + quad * 16 + rl) * 8);
    *dst = packed;

    // reduce partial sums across the 16 lanes sharing this row (xor<16 stays in group)
    #pragma unroll
    for (int off = 8; off > 0; off >>= 1) s += __shfl_xor(s, off);
    if (g == 0) sq[row] = s;
}

// Kernel 2: one 128x128 output tile per block; 4 waves in 2x2, each 64x64
// via 4x4 tiles of 16x16x32 bf16 MFMA, K=128 = 4 ksteps. Fragment loads are
// coalesced dwordx4 from the swizzled L2-resident fbT.
__global__ __launch_bounds__(256) void fs_gemm_kernel(
        const unsigned short* __restrict__ fbT, const float* __restrict__ sq,
        float* __restrict__ out) {
    const int ti   = blockIdx.x;          // A row-tile (128 rows)
    const int tj   = blockIdx.y;          // B row-tile (= output cols)
    const int wid  = threadIdx.x >> 6;
    const int lane = threadIdx.x & 63;
    const int wm   = wid >> 1, wn = wid & 1;
    const int l15  = lane & 15;
    const int quad = lane >> 4;

    const int arow = ti * 128 + wm * 64;  // A rows this wave covers (+0..63)
    const int brow = tj * 128 + wn * 64;  // B rows (= output cols)

    // fragment base: rt16 index (16-row granularity)
    const int rta = ti * 8 + wm * 4;      // +m
    const int rtb = tj * 8 + wn * 4;      // +n

    float4v acc[4][4];
    #pragma unroll
    for (int m = 0; m < 4; ++m)
        #pragma unroll
        for (int n = 0; n < 4; ++n)
            acc[m][n] = (float4v){0.f, 0.f, 0.f, 0.f};

    #pragma unroll
    for (int ks = 0; ks < 4; ++ks) {
        short8 a[4], b[4];
        #pragma unroll
        for (int m = 0; m < 4; ++m)
            a[m] = *(const short8*)(fbT + (size_t)((rta + m) * 4 + ks) * 512 + lane * 8);
        #pragma unroll
        for (int n = 0; n < 4; ++n)
            b[n] = *(const short8*)(fbT + (size_t)((rtb + n) * 4 + ks) * 512 + lane * 8);
        #pragma unroll
        for (int m = 0; m < 4; ++m)
            #pragma unroll
            for (int n = 0; n < 4; ++n)
                acc[m][n] = __builtin_amdgcn_mfma_f32_16x16x32_bf16(
                    a[m], b[n], acc[m][n], 0, 0, 0);
    }

    // Epilogue. C/D layout (16x16): col = l15, row = quad*4 + r.
    // Write transposed (out is symmetric, MFMA dot is bitwise symmetric):
    // out[col*N + row], so each lane stores float4 over r (consecutive rows).
    #pragma unroll
    for (int n = 0; n < 4; ++n) {
        const int   col = brow + n * 16 + l15;
        const float sqc = sq[col];
        float* outcol = out + (size_t)col * FS_N;
        #pragma unroll
        for (int m = 0; m < 4; ++m) {
            const int rbase = arow + m * 16 + quad * 4;
            const float4v sqr = *(const float4v*)(sq + rbase);
            float4v o;
            #pragma unroll
            for (int r = 0; r < 4; ++r) {
                float d2 = sqr[r] + sqc - 2.0f * acc[m][n][r];
                d2 = fmaxf(d2, 0.0f);
                o[r] = -__builtin_sqrtf(d2);
            }
            *(float4v*)(outcol + rbase) = o;
        }
    }
}

extern "C" void kernel_launch(void* const* d_in, const int* in_sizes, int n_in,
                              void* d_out, int out_size, void* d_ws, size_t ws_size,
                              hipStream_t stream) {
    const float* features = (const float*)d_in[0];
    float*       out      = (float*)d_out;

    // ws layout: [0, 2MB) swizzled bf16 features; then fp32 row sum-of-squares
    unsigned short* fbT = (unsigned short*)d_ws;
    float*          sq  = (float*)((char*)d_ws + (size_t)FS_N * FS_D * sizeof(unsigned short));

    fs_convert_kernel<<<FS_N / 16, 256, 0, stream>>>(features, fbT, sq);

    dim3 grid(FS_N / 128, FS_N / 128);
    fs_gemm_kernel<<<grid, 256, 0, stream>>>(fbT, sq, out);
}